// Round 1
// 381.281 us; speedup vs baseline: 1.0702x; 1.0702x over previous
//
#include <hip/hip_runtime.h>
#include <hip/hip_bf16.h>
#include <math.h>
#include <stdint.h>

// TreeLSTM on MFMA: L=16384, D=256, 5 gates, 15 levels, proj to 5.
// Split-precision bf16 (hi+lo) GEMMs: A*B ~= Ahi*Bhi + Alo*Bhi + Ahi*Blo.
// R1: A staged in MFMA-frag order (conflict-free lane-linear LDS reads),
//     JT=2 col-slots per block, double-buffered single-barrier K-loop.

typedef __attribute__((ext_vector_type(8))) short     bf16x8;
typedef __attribute__((ext_vector_type(4))) float     f32x4;
typedef __attribute__((ext_vector_type(8))) unsigned short u16x8;

#define NGATE 5

__device__ __forceinline__ uint16_t f2bf(float f) {
    uint32_t u = __builtin_bit_cast(uint32_t, f);
    u = (u + 0x7fffu + ((u >> 16) & 1u)) >> 16;
    return (uint16_t)u;
}
__device__ __forceinline__ float bf2f(uint16_t h) {
    uint32_t u = ((uint32_t)h) << 16;
    return __builtin_bit_cast(float, u);
}
__device__ __forceinline__ float sigf(float x) { return 1.0f / (1.0f + __expf(-x)); }
__device__ __forceinline__ float tanhfast(float x) {
    float e = __expf(2.0f * x);          // bounded inputs (|x| < ~20) -> no inf
    return (e - 1.0f) / (e + 1.0f);
}

__device__ __forceinline__ void gld_lds16(const void* g, void* l) {
    __builtin_amdgcn_global_load_lds(
        (const __attribute__((address_space(1))) void*)g,
        (__attribute__((address_space(3))) void*)l,
        16, 0, 0);
}

// ---- pack weights into MFMA B-frag order, split hi/lo ----------------------
// dst[( nt*KT + kt )*64 + lane][j]  =  W[kt*32 + (lane>>4)*8 + j][nt*16 + (lane&15)]
// W rows: k<256 from W0, k>=256 from W1 (both row-major K x 1280).
__global__ __launch_bounds__(256) void pack_w_kernel(
    const float* __restrict__ W0, const float* __restrict__ W1, int KT,
    uint16_t* __restrict__ dhi, uint16_t* __restrict__ dlo)
{
    int gid = blockIdx.x * 256 + threadIdx.x;
    int total = 80 * KT * 64;
    if (gid >= total) return;
    int lane = gid & 63;
    int n  = ((gid >> 6) / KT) * 16 + (lane & 15);
    int kt = (gid >> 6) % KT;
    int k0 = kt * 32 + (lane >> 4) * 8;
    u16x8 vh, vl;
    #pragma unroll
    for (int j = 0; j < 8; ++j) {
        int k = k0 + j;
        const float* src = (k < 256) ? (W0 + (size_t)k * 1280)
                                     : (W1 + (size_t)(k - 256) * 1280);
        float v = src[n];
        uint16_t h = f2bf(v);
        vh[j] = h;
        vl[j] = f2bf(v - bf2f(h));
    }
    *(u16x8*)(dhi + (size_t)gid * 8) = vh;
    *(u16x8*)(dlo + (size_t)gid * 8) = vl;
}

// ---- fused level GEMM + LSTM cell ------------------------------------------
// Block: 256 thr = 4 waves. Tile: BM rows x (NGATE * JT * 16) cols.
// grid.y = jn in [0, 16/JT): block covers col-slots jn*JT .. jn*JT+JT-1 of
// each gate; output dims d = (jn*JT+js)*16 + (lane&15).
// A staged in frag order: chunk ci (16 rows x 32 k) holds lane-linear frags:
//   elem at chunk*512 + lane*8 + j  ==  A[ci*16 + (lane&15)][kt*32 + (lane>>4)*8 + j]
// Double-buffered (lX0/lX1), one __syncthreads per K-step; stage for step
// k+1 is issued BEFORE the MFMAs of step k so global latency hides under MFMA.
template<int BM, int KT, int JT, bool LVL0>
__global__ __launch_bounds__(256) void lvl_gemm(
    const uint16_t* __restrict__ Ahi, const uint16_t* __restrict__ Alo, // row-major, stride K
    const int* __restrict__ tokens, const float* __restrict__ emb,      // LVL0 only
    const uint16_t* __restrict__ Bhi, const uint16_t* __restrict__ Blo, // packed frag order
    const float* __restrict__ b,
    const float* __restrict__ c_prev,                                    // null for LVL0
    uint16_t* __restrict__ h_hi_out, uint16_t* __restrict__ h_lo_out,
    float* __restrict__ c_out, int n)
{
    constexpr int K   = KT * 32;
    constexpr int MT  = BM / 64;          // m-tiles per wave
    constexpr int ACH = BM / 16;          // 1KB A-chunks per matrix (hi or lo)
    constexpr int NC  = NGATE * JT * 2;   // B chunks per k-step (g x js x hi/lo)

    __shared__ __align__(16) uint16_t lA0[2][BM * 32];   // [hi/lo][frag-order]
    __shared__ __align__(16) uint16_t lA1[2][BM * 32];
    __shared__ __align__(16) uint16_t lB0[NC * 512];
    __shared__ __align__(16) uint16_t lB1[NC * 512];

    const int tid  = threadIdx.x;
    const int wave = tid >> 6;
    const int lane = tid & 63;
    const int quad = lane >> 4;
    const int l15  = lane & 15;
    const int r0   = blockIdx.x * BM;
    const int jn   = blockIdx.y;

    f32x4 acc[MT][JT][NGATE] = {};

    // LVL0 per-thread gather setup (row0 in [0,BM), kh in {0,1} -> 16 k each)
    const int row0 = tid >> 1;
    const int kh   = tid & 1;
    const float* esrc = nullptr;
    if constexpr (LVL0) {
        int tok = tokens[r0 + row0];
        esrc = emb + (size_t)tok * 256 + kh * 16;
    }

    auto stageB = [&](uint16_t* dB, int kt) {
        for (int c = wave; c < NC; c += 4) {
            int hl = c & 1, gj = c >> 1;                 // gj = g*JT + js
            const uint16_t* src = hl ? Blo : Bhi;
            int nt = (gj / JT) * 16 + jn * JT + (gj % JT);
            gld_lds16(src + ((size_t)(nt * KT + kt) * 64 + lane) * 8,
                      dB + c * 512);
        }
    };
    auto stageA = [&](uint16_t* dA0, uint16_t* dA1, int kt) {
        for (int c = wave; c < 2 * ACH; c += 4) {
            int mat = (c >= ACH) ? 1 : 0;
            int ci  = mat ? (c - ACH) : c;
            const uint16_t* src = mat ? Alo : Ahi;
            uint16_t* dst = (mat ? dA1 : dA0) + ci * 512;
            // frag-order source permutation: row <- lane&15, k-chunk <- lane>>4
            int row = r0 + ci * 16 + l15;
            row = min(row, n - 1);
            gld_lds16(src + (size_t)row * K + kt * 32 + quad * 8, dst);
        }
    };
    auto stage0 = [&](uint16_t* dA0, uint16_t* dA1, uint16_t* dB, int kt) {
        stageB(dB, kt);
        const float* s = esrc + kt * 32;
        float v[16];
        #pragma unroll
        for (int q = 0; q < 4; ++q) {
            float4 f = *(const float4*)(s + 4 * q);
            v[4*q+0] = f.x; v[4*q+1] = f.y; v[4*q+2] = f.z; v[4*q+3] = f.w;
        }
        u16x8 h0, h1, l0, l1;
        #pragma unroll
        for (int j = 0; j < 8; ++j) {
            uint16_t h = f2bf(v[j]);     h0[j] = h; l0[j] = f2bf(v[j]     - bf2f(h));
            uint16_t g2 = f2bf(v[j+8]);  h1[j] = g2; l1[j] = f2bf(v[j+8] - bf2f(g2));
        }
        // frag-order write: chunk = row0>>4, kq = kh*2 + {0,1}, rl = row0&15
        int o = (row0 >> 4) * 512 + kh * 256 + (row0 & 15) * 8;
        *(u16x8*)(dA0 + o)       = h0;
        *(u16x8*)(dA0 + o + 128) = h1;
        *(u16x8*)(dA1 + o)       = l0;
        *(u16x8*)(dA1 + o + 128) = l1;
    };
    auto compute = [&](const uint16_t* A0, const uint16_t* A1, const uint16_t* Bx) {
        bf16x8 ah[MT], al[MT];
        #pragma unroll
        for (int mt = 0; mt < MT; ++mt) {
            int ci = wave * MT + mt;
            ah[mt] = *(const bf16x8*)(A0 + ci * 512 + lane * 8);
            al[mt] = *(const bf16x8*)(A1 + ci * 512 + lane * 8);
        }
        #pragma unroll
        for (int g = 0; g < NGATE; ++g) {
            #pragma unroll
            for (int js = 0; js < JT; ++js) {
                const uint16_t* bp = Bx + (g * JT + js) * 1024;
                bf16x8 bh = *(const bf16x8*)(bp + lane * 8);
                bf16x8 bl = *(const bf16x8*)(bp + 512 + lane * 8);
                #pragma unroll
                for (int mt = 0; mt < MT; ++mt) {
                    acc[mt][js][g] = __builtin_amdgcn_mfma_f32_16x16x32_bf16(ah[mt], bh, acc[mt][js][g], 0, 0, 0);
                    acc[mt][js][g] = __builtin_amdgcn_mfma_f32_16x16x32_bf16(al[mt], bh, acc[mt][js][g], 0, 0, 0);
                    acc[mt][js][g] = __builtin_amdgcn_mfma_f32_16x16x32_bf16(ah[mt], bl, acc[mt][js][g], 0, 0, 0);
                }
            }
        }
    };

    // ---------------- pipelined K loop (2x unrolled, static buffers) --------
    if constexpr (LVL0) stage0(lA0[0], lA0[1], lB0, 0);
    else { stageA(lA0[0], lA0[1], 0); stageB(lB0, 0); }
    __syncthreads();

    for (int kt = 0; kt < KT; kt += 2) {
        if constexpr (LVL0) stage0(lA1[0], lA1[1], lB1, kt + 1);
        else { stageA(lA1[0], lA1[1], kt + 1); stageB(lB1, kt + 1); }
        compute(lA0[0], lA0[1], lB0);
        __syncthreads();

        if (kt + 2 < KT) {
            if constexpr (LVL0) stage0(lA0[0], lA0[1], lB0, kt + 2);
            else { stageA(lA0[0], lA0[1], kt + 2); stageB(lB0, kt + 2); }
        }
        compute(lA1[0], lA1[1], lB1);
        __syncthreads();
    }

    // ---------------- fused cell epilogue ----------------
    const int d0 = (jn * JT) * 16 + l15;
    float bg[JT][NGATE];
    #pragma unroll
    for (int js = 0; js < JT; ++js)
        #pragma unroll
        for (int g = 0; g < NGATE; ++g) bg[js][g] = b[g * 256 + d0 + js * 16];

    #pragma unroll
    for (int mt = 0; mt < MT; ++mt) {
        int rb = r0 + wave * (MT * 16) + mt * 16 + quad * 4;
        #pragma unroll
        for (int v = 0; v < 4; ++v) {
            int row = rb + v;
            if (row < n) {
                #pragma unroll
                for (int js = 0; js < JT; ++js) {
                    int d = d0 + js * 16;
                    float gi = acc[mt][js][0][v] + bg[js][0];
                    float fl = acc[mt][js][1][v] + bg[js][1];
                    float fr = acc[mt][js][2][v] + bg[js][2];
                    float go = acc[mt][js][3][v] + bg[js][3];
                    float gu = acc[mt][js][4][v] + bg[js][4];
                    float cc;
                    if constexpr (LVL0) {
                        cc = sigf(gi) * tanhfast(gu);
                        (void)fl; (void)fr;
                    } else {
                        float cl = c_prev[(size_t)(2 * row) * 256 + d];
                        float cr = c_prev[(size_t)(2 * row + 1) * 256 + d];
                        cc = sigf(gi) * tanhfast(gu) + sigf(fl) * cl + sigf(fr) * cr;
                    }
                    float hh = sigf(go) * tanhfast(cc);
                    uint16_t hb = f2bf(hh);
                    h_hi_out[(size_t)row * 256 + d] = hb;
                    h_lo_out[(size_t)row * 256 + d] = f2bf(hh - bf2f(hb));
                    c_out[(size_t)row * 256 + d] = cc;
                }
            }
        }
    }
}

// ---- projection: out = hidden @ Wp + bp, hidden reconstructed hi+lo --------
__global__ __launch_bounds__(256) void proj_kernel(
    const uint16_t* __restrict__ h_hi, const uint16_t* __restrict__ h_lo,
    const float* __restrict__ Wp, const float* __restrict__ bp,
    float* __restrict__ out, int n)
{
    const int wave = blockIdx.x * 4 + (threadIdx.x >> 6);
    const int lane = threadIdx.x & 63;
    if (wave >= n) return;

    const uint16_t* hh = h_hi + (size_t)wave * 256;
    const uint16_t* hl = h_lo + (size_t)wave * 256;
    float s[5] = {0.f, 0.f, 0.f, 0.f, 0.f};
    #pragma unroll
    for (int q = 0; q < 4; ++q) {
        int dd = lane + 64 * q;
        float hv = bf2f(hh[dd]) + bf2f(hl[dd]);
        #pragma unroll
        for (int j = 0; j < 5; ++j) s[j] += hv * Wp[dd * 5 + j];
    }
    #pragma unroll
    for (int off = 32; off; off >>= 1)
        #pragma unroll
        for (int j = 0; j < 5; ++j) s[j] += __shfl_down(s[j], off);

    if (lane == 0) {
        #pragma unroll
        for (int j = 0; j < 5; ++j) out[(size_t)wave * 5 + j] = s[j] + bp[j];
    }
}

extern "C" void kernel_launch(void* const* d_in, const int* in_sizes, int n_in,
                              void* d_out, int out_size, void* d_ws, size_t ws_size,
                              hipStream_t stream)
{
    const int*   tokens = (const int*)  d_in[0];
    const float* emb    = (const float*)d_in[1];
    const float* Wx     = (const float*)d_in[2];
    const float* Ul     = (const float*)d_in[3];
    const float* Ur     = (const float*)d_in[4];
    const float* b      = (const float*)d_in[5];
    const float* Wp     = (const float*)d_in[6];
    const float* bp     = (const float*)d_in[7];
    float* out = (float*)d_out;

    // workspace carve (total ~62.6 MB)
    uint8_t* w = (uint8_t*)d_ws;
    uint16_t* h_hi = (uint16_t*)w;  w += (size_t)32767 * 256 * 2;
    uint16_t* h_lo = (uint16_t*)w;  w += (size_t)32767 * 256 * 2;
    float*    cA   = (float*)w;     w += (size_t)16384 * 256 * 4;
    float*    cB   = (float*)w;     w += (size_t)8192  * 256 * 4;
    uint16_t* BxH  = (uint16_t*)w;  w += (size_t)80 * 8  * 64 * 8 * 2;
    uint16_t* BxL  = (uint16_t*)w;  w += (size_t)80 * 8  * 64 * 8 * 2;
    uint16_t* BuH  = (uint16_t*)w;  w += (size_t)80 * 16 * 64 * 8 * 2;
    uint16_t* BuL  = (uint16_t*)w;  w += (size_t)80 * 16 * 64 * 8 * 2;

    pack_w_kernel<<<(80 * 8  * 64) / 256, 256, 0, stream>>>(Wx, Wx, 8,  BxH, BxL);
    pack_w_kernel<<<(80 * 16 * 64) / 256, 256, 0, stream>>>(Ul, Ur, 16, BuH, BuL);

    int off[16];
    off[0] = 0;
    for (int t = 0; t < 15; ++t) off[t + 1] = off[t] + (16384 >> t);

    // level 0: 128x(5x32) tile, JT=2 -> grid (128, 8)
    lvl_gemm<128, 8, 2, true><<<dim3(16384 / 128, 8), 256, 0, stream>>>(
        nullptr, nullptr, tokens, emb, BxH, BxL, b, nullptr,
        h_hi, h_lo, cA, 16384);

    // levels 1..14
    for (int t = 1; t <= 14; ++t) {
        int n = 16384 >> t;
        const uint16_t* Ah = h_hi + (size_t)off[t - 1] * 256;
        const uint16_t* Al = h_lo + (size_t)off[t - 1] * 256;
        float* c_in  = (t % 2 == 0) ? cB : cA;
        float* c_out = (t % 2 == 0) ? cA : cB;
        uint16_t* Hh = h_hi + (size_t)off[t] * 256;
        uint16_t* Hl = h_lo + (size_t)off[t] * 256;
        if (n >= 4096) {
            lvl_gemm<128, 16, 2, false><<<dim3(n / 128, 8), 256, 0, stream>>>(
                Ah, Al, nullptr, nullptr, BuH, BuL, b, c_in, Hh, Hl, c_out, n);
        } else if (n >= 2048) {
            lvl_gemm<64, 16, 2, false><<<dim3(n / 64, 8), 256, 0, stream>>>(
                Ah, Al, nullptr, nullptr, BuH, BuL, b, c_in, Hh, Hl, c_out, n);
        } else {
            int gx = (n + 63) / 64; if (gx < 1) gx = 1;
            lvl_gemm<64, 16, 1, false><<<dim3(gx, 16), 256, 0, stream>>>(
                Ah, Al, nullptr, nullptr, BuH, BuL, b, c_in, Hh, Hl, c_out, n);
        }
    }

    int total = off[15];  // 32767
    proj_kernel<<<(total + 3) / 4, 256, 0, stream>>>(h_hi, h_lo, Wp, bp, out, total);
}

// Round 2
// 340.288 us; speedup vs baseline: 1.1991x; 1.1205x over previous
//
#include <hip/hip_runtime.h>
#include <hip/hip_bf16.h>
#include <math.h>
#include <stdint.h>

// TreeLSTM on MFMA: L=16384, D=256, 5 gates, 15 levels, proj to 5.
// Split-precision bf16 (hi+lo) GEMMs: A*B ~= Ahi*Bhi + Alo*Bhi + Ahi*Blo.
// R2: A fragments are wave-private -> load A straight into registers
//     (double-buffered), LDS holds only B (40KB) -> 4 blocks/CU.
//     Level 0 gathers emb per-lane and converts in-register (no ds round trip).

typedef __attribute__((ext_vector_type(8))) short     bf16x8;
typedef __attribute__((ext_vector_type(4))) float     f32x4;
typedef __attribute__((ext_vector_type(8))) unsigned short u16x8;

#define NGATE 5

__device__ __forceinline__ uint16_t f2bf(float f) {
    uint32_t u = __builtin_bit_cast(uint32_t, f);
    u = (u + 0x7fffu + ((u >> 16) & 1u)) >> 16;
    return (uint16_t)u;
}
__device__ __forceinline__ float bf2f(uint16_t h) {
    uint32_t u = ((uint32_t)h) << 16;
    return __builtin_bit_cast(float, u);
}
__device__ __forceinline__ float sigf(float x) { return 1.0f / (1.0f + __expf(-x)); }
__device__ __forceinline__ float tanhfast(float x) {
    float e = __expf(2.0f * x);          // bounded inputs (|x| < ~20) -> no inf
    return (e - 1.0f) / (e + 1.0f);
}

__device__ __forceinline__ void gld_lds16(const void* g, void* l) {
    __builtin_amdgcn_global_load_lds(
        (const __attribute__((address_space(1))) void*)g,
        (__attribute__((address_space(3))) void*)l,
        16, 0, 0);
}

// ---- pack weights into MFMA B-frag order, split hi/lo ----------------------
// dst[( nt*KT + kt )*64 + lane][j]  =  W[kt*32 + (lane>>4)*8 + j][nt*16 + (lane&15)]
// W rows: k<256 from W0, k>=256 from W1 (both row-major K x 1280).
__global__ __launch_bounds__(256) void pack_w_kernel(
    const float* __restrict__ W0, const float* __restrict__ W1, int KT,
    uint16_t* __restrict__ dhi, uint16_t* __restrict__ dlo)
{
    int gid = blockIdx.x * 256 + threadIdx.x;
    int total = 80 * KT * 64;
    if (gid >= total) return;
    int lane = gid & 63;
    int n  = ((gid >> 6) / KT) * 16 + (lane & 15);
    int kt = (gid >> 6) % KT;
    int k0 = kt * 32 + (lane >> 4) * 8;
    u16x8 vh, vl;
    #pragma unroll
    for (int j = 0; j < 8; ++j) {
        int k = k0 + j;
        const float* src = (k < 256) ? (W0 + (size_t)k * 1280)
                                     : (W1 + (size_t)(k - 256) * 1280);
        float v = src[n];
        uint16_t h = f2bf(v);
        vh[j] = h;
        vl[j] = f2bf(v - bf2f(h));
    }
    *(u16x8*)(dhi + (size_t)gid * 8) = vh;
    *(u16x8*)(dlo + (size_t)gid * 8) = vl;
}

// ---- fused level GEMM + LSTM cell ------------------------------------------
// Block: 256 thr = 4 waves. Tile: BM rows x (NGATE * JT * 16) cols.
// grid.y = jn in [0, 16/JT): output dims d = (jn*JT+js)*16 + (lane&15).
// A fragments are WAVE-PRIVATE: lane (quad,l15) of wave w needs exactly
//   A[r0 + (w*MT+mt)*16 + l15][kt*32 + quad*8 .. +8)  (16B)
// -> loaded directly global->VGPR, double-buffered across kt (no LDS).
// B staged via global_load_lds into LDS (shared by all 4 waves), dbuf.
// One __syncthreads per kt; its vmcnt(0) drain covers both prefetch streams.
template<int BM, int KT, int JT, bool LVL0>
__global__ __launch_bounds__(256) void lvl_gemm(
    const uint16_t* __restrict__ Ahi, const uint16_t* __restrict__ Alo, // row-major, stride K
    const int* __restrict__ tokens, const float* __restrict__ emb,      // LVL0 only
    const uint16_t* __restrict__ Bhi, const uint16_t* __restrict__ Blo, // packed frag order
    const float* __restrict__ b,
    const float* __restrict__ c_prev,                                    // null for LVL0
    uint16_t* __restrict__ h_hi_out, uint16_t* __restrict__ h_lo_out,
    float* __restrict__ c_out, int n)
{
    constexpr int K   = KT * 32;
    constexpr int MT  = BM / 64;          // m-tiles per wave
    constexpr int NC  = NGATE * JT * 2;   // B chunks per k-step (g x js x hi/lo)

    __shared__ __align__(16) uint16_t sB0[NC * 512];
    __shared__ __align__(16) uint16_t sB1[NC * 512];

    const int tid  = threadIdx.x;
    const int wave = tid >> 6;
    const int lane = tid & 63;
    const int quad = lane >> 4;
    const int l15  = lane & 15;
    const int r0   = blockIdx.x * BM;
    const int jn   = blockIdx.y;

    f32x4 acc[MT][JT][NGATE] = {};

    // per-lane A source pointers (fixed row, k advances by kt*32)
    const uint16_t* aph[MT];
    const uint16_t* apl[MT];
    const float*    ebase[MT];
    #pragma unroll
    for (int mt = 0; mt < MT; ++mt) {
        int row = r0 + (wave * MT + mt) * 16 + l15;
        row = min(row, n - 1);
        if constexpr (LVL0) {
            int tok = tokens[row];
            ebase[mt] = emb + (size_t)tok * 256 + quad * 8;
        } else {
            aph[mt] = Ahi + (size_t)row * K + quad * 8;
            apl[mt] = Alo + (size_t)row * K + quad * 8;
        }
    }

    auto stageB = [&](uint16_t* dB, int kt) {
        #pragma unroll
        for (int c = wave; c < NC; c += 4) {
            int hl = c & 1, gj = c >> 1;                 // gj = g*JT + js
            const uint16_t* src = hl ? Blo : Bhi;
            int nt = (gj / JT) * 16 + jn * JT + (gj % JT);
            gld_lds16(src + ((size_t)(nt * KT + kt) * 64 + lane) * 8,
                      dB + c * 512);
        }
    };
    // level>=1: raw bf16x8 A loads
    auto loadAn = [&](bf16x8 (&ah)[MT], bf16x8 (&al)[MT], int kt) {
        #pragma unroll
        for (int mt = 0; mt < MT; ++mt) {
            ah[mt] = *(const bf16x8*)(aph[mt] + kt * 32);
            al[mt] = *(const bf16x8*)(apl[mt] + kt * 32);
        }
    };
    // level0: raw emb float loads (convert at consume time)
    auto loadA0 = [&](float4 (&e)[MT][2], int kt) {
        #pragma unroll
        for (int mt = 0; mt < MT; ++mt) {
            const float4* p = (const float4*)(ebase[mt] + kt * 32);
            e[mt][0] = p[0];
            e[mt][1] = p[1];
        }
    };
    auto cvtA0 = [&](const float4 (&e)[MT][2], bf16x8 (&ah)[MT], bf16x8 (&al)[MT]) {
        #pragma unroll
        for (int mt = 0; mt < MT; ++mt) {
            float fv[8];
            fv[0] = e[mt][0].x; fv[1] = e[mt][0].y; fv[2] = e[mt][0].z; fv[3] = e[mt][0].w;
            fv[4] = e[mt][1].x; fv[5] = e[mt][1].y; fv[6] = e[mt][1].z; fv[7] = e[mt][1].w;
            #pragma unroll
            for (int j = 0; j < 8; ++j) {
                uint16_t h = f2bf(fv[j]);
                ah[mt][j] = (short)h;
                al[mt][j] = (short)f2bf(fv[j] - bf2f(h));
            }
        }
    };
    auto mfma_all = [&](const bf16x8 (&ah)[MT], const bf16x8 (&al)[MT],
                        const uint16_t* Bx) {
        #pragma unroll
        for (int g = 0; g < NGATE; ++g) {
            #pragma unroll
            for (int js = 0; js < JT; ++js) {
                const uint16_t* bp = Bx + (g * JT + js) * 1024;
                bf16x8 bh = *(const bf16x8*)(bp + lane * 8);
                bf16x8 bl = *(const bf16x8*)(bp + 512 + lane * 8);
                #pragma unroll
                for (int mt = 0; mt < MT; ++mt) {
                    acc[mt][js][g] = __builtin_amdgcn_mfma_f32_16x16x32_bf16(ah[mt], bh, acc[mt][js][g], 0, 0, 0);
                    acc[mt][js][g] = __builtin_amdgcn_mfma_f32_16x16x32_bf16(al[mt], bh, acc[mt][js][g], 0, 0, 0);
                    acc[mt][js][g] = __builtin_amdgcn_mfma_f32_16x16x32_bf16(ah[mt], bl, acc[mt][js][g], 0, 0, 0);
                }
            }
        }
    };

    // ---------------- pipelined K loop (2x unrolled, named reg slots) -------
    if constexpr (LVL0) {
        float4 eA[MT][2], eB[MT][2];
        loadA0(eA, 0);
        stageB(sB0, 0);
        __syncthreads();                       // vmcnt(0): eA + sB0 ready
        for (int kt = 0; kt < KT; kt += 2) {
            loadA0(eB, kt + 1);
            stageB(sB1, kt + 1);
            {
                bf16x8 ah[MT], al[MT];
                cvtA0(eA, ah, al);
                mfma_all(ah, al, sB0);
            }
            __syncthreads();
            if (kt + 2 < KT) { loadA0(eA, kt + 2); stageB(sB0, kt + 2); }
            {
                bf16x8 ah[MT], al[MT];
                cvtA0(eB, ah, al);
                mfma_all(ah, al, sB1);
            }
            __syncthreads();
        }
    } else {
        bf16x8 hA[MT], lA[MT], hB[MT], lB[MT];
        loadAn(hA, lA, 0);
        stageB(sB0, 0);
        __syncthreads();
        for (int kt = 0; kt < KT; kt += 2) {
            loadAn(hB, lB, kt + 1);
            stageB(sB1, kt + 1);
            mfma_all(hA, lA, sB0);
            __syncthreads();
            if (kt + 2 < KT) { loadAn(hA, lA, kt + 2); stageB(sB0, kt + 2); }
            mfma_all(hB, lB, sB1);
            __syncthreads();
        }
    }

    // ---------------- fused cell epilogue ----------------
    const int d0 = (jn * JT) * 16 + l15;
    float bg[JT][NGATE];
    #pragma unroll
    for (int js = 0; js < JT; ++js)
        #pragma unroll
        for (int g = 0; g < NGATE; ++g) bg[js][g] = b[g * 256 + d0 + js * 16];

    #pragma unroll
    for (int mt = 0; mt < MT; ++mt) {
        int rb = r0 + wave * (MT * 16) + mt * 16 + quad * 4;
        #pragma unroll
        for (int v = 0; v < 4; ++v) {
            int row = rb + v;
            if (row < n) {
                #pragma unroll
                for (int js = 0; js < JT; ++js) {
                    int d = d0 + js * 16;
                    float gi = acc[mt][js][0][v] + bg[js][0];
                    float fl = acc[mt][js][1][v] + bg[js][1];
                    float fr = acc[mt][js][2][v] + bg[js][2];
                    float go = acc[mt][js][3][v] + bg[js][3];
                    float gu = acc[mt][js][4][v] + bg[js][4];
                    float cc;
                    if constexpr (LVL0) {
                        cc = sigf(gi) * tanhfast(gu);
                        (void)fl; (void)fr;
                    } else {
                        float cl = c_prev[(size_t)(2 * row) * 256 + d];
                        float cr = c_prev[(size_t)(2 * row + 1) * 256 + d];
                        cc = sigf(gi) * tanhfast(gu) + sigf(fl) * cl + sigf(fr) * cr;
                    }
                    float hh = sigf(go) * tanhfast(cc);
                    uint16_t hb = f2bf(hh);
                    h_hi_out[(size_t)row * 256 + d] = hb;
                    h_lo_out[(size_t)row * 256 + d] = f2bf(hh - bf2f(hb));
                    c_out[(size_t)row * 256 + d] = cc;
                }
            }
        }
    }
}

// ---- projection: out = hidden @ Wp + bp, hidden reconstructed hi+lo --------
__global__ __launch_bounds__(256) void proj_kernel(
    const uint16_t* __restrict__ h_hi, const uint16_t* __restrict__ h_lo,
    const float* __restrict__ Wp, const float* __restrict__ bp,
    float* __restrict__ out, int n)
{
    const int wave = blockIdx.x * 4 + (threadIdx.x >> 6);
    const int lane = threadIdx.x & 63;
    if (wave >= n) return;

    const uint16_t* hh = h_hi + (size_t)wave * 256;
    const uint16_t* hl = h_lo + (size_t)wave * 256;
    float s[5] = {0.f, 0.f, 0.f, 0.f, 0.f};
    #pragma unroll
    for (int q = 0; q < 4; ++q) {
        int dd = lane + 64 * q;
        float hv = bf2f(hh[dd]) + bf2f(hl[dd]);
        #pragma unroll
        for (int j = 0; j < 5; ++j) s[j] += hv * Wp[dd * 5 + j];
    }
    #pragma unroll
    for (int off = 32; off; off >>= 1)
        #pragma unroll
        for (int j = 0; j < 5; ++j) s[j] += __shfl_down(s[j], off);

    if (lane == 0) {
        #pragma unroll
        for (int j = 0; j < 5; ++j) out[(size_t)wave * 5 + j] = s[j] + bp[j];
    }
}

extern "C" void kernel_launch(void* const* d_in, const int* in_sizes, int n_in,
                              void* d_out, int out_size, void* d_ws, size_t ws_size,
                              hipStream_t stream)
{
    const int*   tokens = (const int*)  d_in[0];
    const float* emb    = (const float*)d_in[1];
    const float* Wx     = (const float*)d_in[2];
    const float* Ul     = (const float*)d_in[3];
    const float* Ur     = (const float*)d_in[4];
    const float* b      = (const float*)d_in[5];
    const float* Wp     = (const float*)d_in[6];
    const float* bp     = (const float*)d_in[7];
    float* out = (float*)d_out;

    // workspace carve (total ~62.6 MB)
    uint8_t* w = (uint8_t*)d_ws;
    uint16_t* h_hi = (uint16_t*)w;  w += (size_t)32767 * 256 * 2;
    uint16_t* h_lo = (uint16_t*)w;  w += (size_t)32767 * 256 * 2;
    float*    cA   = (float*)w;     w += (size_t)16384 * 256 * 4;
    float*    cB   = (float*)w;     w += (size_t)8192  * 256 * 4;
    uint16_t* BxH  = (uint16_t*)w;  w += (size_t)80 * 8  * 64 * 8 * 2;
    uint16_t* BxL  = (uint16_t*)w;  w += (size_t)80 * 8  * 64 * 8 * 2;
    uint16_t* BuH  = (uint16_t*)w;  w += (size_t)80 * 16 * 64 * 8 * 2;
    uint16_t* BuL  = (uint16_t*)w;  w += (size_t)80 * 16 * 64 * 8 * 2;

    pack_w_kernel<<<(80 * 8  * 64) / 256, 256, 0, stream>>>(Wx, Wx, 8,  BxH, BxL);
    pack_w_kernel<<<(80 * 16 * 64) / 256, 256, 0, stream>>>(Ul, Ur, 16, BuH, BuL);

    int off[16];
    off[0] = 0;
    for (int t = 0; t < 15; ++t) off[t + 1] = off[t] + (16384 >> t);

    // level 0: 128x(5x32) tile, JT=2 -> grid (128, 8)
    lvl_gemm<128, 8, 2, true><<<dim3(16384 / 128, 8), 256, 0, stream>>>(
        nullptr, nullptr, tokens, emb, BxH, BxL, b, nullptr,
        h_hi, h_lo, cA, 16384);

    // levels 1..14
    for (int t = 1; t <= 14; ++t) {
        int n = 16384 >> t;
        const uint16_t* Ah = h_hi + (size_t)off[t - 1] * 256;
        const uint16_t* Al = h_lo + (size_t)off[t - 1] * 256;
        float* c_in  = (t % 2 == 0) ? cB : cA;
        float* c_out = (t % 2 == 0) ? cA : cB;
        uint16_t* Hh = h_hi + (size_t)off[t] * 256;
        uint16_t* Hl = h_lo + (size_t)off[t] * 256;
        if (n >= 4096) {
            lvl_gemm<128, 16, 2, false><<<dim3(n / 128, 8), 256, 0, stream>>>(
                Ah, Al, nullptr, nullptr, BuH, BuL, b, c_in, Hh, Hl, c_out, n);
        } else if (n >= 2048) {
            lvl_gemm<64, 16, 2, false><<<dim3(n / 64, 8), 256, 0, stream>>>(
                Ah, Al, nullptr, nullptr, BuH, BuL, b, c_in, Hh, Hl, c_out, n);
        } else {
            int gx = (n + 63) / 64; if (gx < 1) gx = 1;
            lvl_gemm<64, 16, 1, false><<<dim3(gx, 16), 256, 0, stream>>>(
                Ah, Al, nullptr, nullptr, BuH, BuL, b, c_in, Hh, Hl, c_out, n);
        }
    }

    int total = off[15];  // 32767
    proj_kernel<<<(total + 3) / 4, 256, 0, stream>>>(h_hi, h_lo, Wp, bp, out, total);
}